// Round 9
// baseline (17.777 us; speedup 1.0000x reference)
//
#include <hip/hip_runtime.h>
#include <math.h>

// ---------------------------------------------------------------------------
// Compile-time PGA Cl(3,0,1) tables. Basis ordering matches reference:
//   1, e0, e1, e2, e3, e01, e02, e03, e12, e13, e23, e012, e013, e023, e123, e0123
// Bitmask: bit0=e0, bit1=e1, bit2=e2, bit3=e3.
// ---------------------------------------------------------------------------
namespace ct {

constexpr int MASK[16] = {0, 1, 2, 4, 8, 3, 5, 9, 6, 10, 12, 7, 11, 13, 14, 15};
constexpr int IDX[16]  = {0, 1, 2, 5, 3, 6, 8, 11, 4, 7, 9, 12, 10, 13, 14, 15};
constexpr int GRADE[16] = {0, 1, 1, 1, 1, 2, 2, 2, 2, 2, 2, 3, 3, 3, 3, 4};

constexpr int popc(int v) { int c = 0; while (v) { c += v & 1; v >>= 1; } return c; }

constexpr int rs(int a, int b) {
    int s = 0;
    a >>= 1;
    while (a) { s += popc(a & b); a >>= 1; }
    return (s & 1) ? -1 : 1;
}

struct Tab { int sgn[16][16]; int idx[16][16]; };

constexpr Tab make_gp() {
    Tab t{};
    for (int i = 0; i < 16; ++i)
        for (int j = 0; j < 16; ++j) {
            int a = MASK[i], b = MASK[j];
            if (a & b & 1) { t.sgn[i][j] = 0; t.idx[i][j] = 0; }
            else           { t.sgn[i][j] = rs(a, b); t.idx[i][j] = IDX[a ^ b]; }
        }
    return t;
}

constexpr Tab make_jn() {
    Tab t{};
    for (int i = 0; i < 16; ++i)
        for (int j = 0; j < 16; ++j) {
            int a = MASK[i], b = MASK[j];
            int ca = 15 ^ a, cb = 15 ^ b;
            if (ca & cb) { t.sgn[i][j] = 0; t.idx[i][j] = 0; }
            else {
                int m = ca | cb;      // wedge in dual space
                int p = 15 ^ m;       // undual
                t.sgn[i][j] = rs(a, ca) * rs(b, cb) * rs(ca, cb) * rs(p, m);
                t.idx[i][j] = IDX[p];
            }
        }
    return t;
}

constexpr Tab GP = make_gp();
constexpr Tab JN = make_jn();

} // namespace ct

// ---------------------------------------------------------------------------
// TWO threads per multivector (p = t&1 owns output half 8p..8p+7).
// Loads/stores: thread t <-> float4 indices 2t, 2t+1 (32 B per thread,
// contiguous coverage, stores mirror loads). Partner half exchanged with
// __shfl_xor(.,1); canonical X[16] assembled with uniform selects.
// Doubles the wave count to 8/SIMD (vs 4) so successive wave generations
// pipeline their read/compute/write phases; halves per-wave registers.
// No LDS, no barriers. Only the two 8-output gather bodies are divergent,
// and all e0-branch cross terms stay within a half (0->1,2->5,3->6,4->7,
// 8->11,9->12,10->13), so no cross-lane traffic after the input exchange.
// ---------------------------------------------------------------------------
__global__ __launch_bounds__(256) void mvffn_kernel(
    const float* __restrict__ x,
    const float* __restrict__ w1,  const float* __restrict__ v1,  const float* __restrict__ b1,
    const float* __restrict__ w2g, const float* __restrict__ v2g, const float* __restrict__ b2g,
    const float* __restrict__ w2j, const float* __restrict__ v2j, const float* __restrict__ b2j,
    float* __restrict__ out, int n2)            // n2 = 2*n half-MV threads
{
    const int t = blockIdx.x * blockDim.x + threadIdx.x;
    if (t >= n2) return;
    const bool podd = (t & 1);

    // ---- load own 32 B: quads {2p, 2p+1} of MV m = t>>1 ----
    const float4* x4 = reinterpret_cast<const float4*>(x);
    float4 A = x4[2 * (size_t)t];
    float4 B = x4[2 * (size_t)t + 1];

    // ---- uniform parameters ----
    float W1[5], W2G[5], W2J[5], V1[4], V2G[4], V2J[4];
    #pragma unroll
    for (int i = 0; i < 5; ++i) { W1[i] = w1[i]; W2G[i] = w2g[i]; W2J[i] = w2j[i]; }
    #pragma unroll
    for (int i = 0; i < 4; ++i) { V1[i] = v1[i]; V2G[i] = v2g[i]; V2J[i] = v2j[i]; }
    const float B1 = b1[0], B2G = b2g[0], B2J = b2j[0];

    // ---- exchange halves with the partner lane (uniform, pre-divergence) ----
    float a0 = A.x, a1 = A.y, a2 = A.z, a3 = A.w;
    float b0 = B.x, b1f = B.y, b2f = B.z, b3 = B.w;
    float sa0 = __shfl_xor(a0, 1), sa1 = __shfl_xor(a1, 1),
          sa2 = __shfl_xor(a2, 1), sa3 = __shfl_xor(a3, 1);
    float sb0 = __shfl_xor(b0, 1), sb1 = __shfl_xor(b1f, 1),
          sb2 = __shfl_xor(b2f, 1), sb3 = __shfl_xor(b3, 1);

    // canonical X: low half = own if p==0 else partner's; high half opposite
    float X[16];
    X[0]  = podd ? sa0 : a0;   X[1]  = podd ? sa1 : a1;
    X[2]  = podd ? sa2 : a2;   X[3]  = podd ? sa3 : a3;
    X[4]  = podd ? sb0 : b0;   X[5]  = podd ? sb1 : b1f;
    X[6]  = podd ? sb2 : b2f;  X[7]  = podd ? sb3 : b3;
    X[8]  = podd ? a0 : sa0;   X[9]  = podd ? a1 : sa1;
    X[10] = podd ? a2 : sa2;   X[11] = podd ? a3 : sa3;
    X[12] = podd ? b0 : sb0;   X[13] = podd ? b1f : sb1;
    X[14] = podd ? b2f : sb2;  X[15] = podd ? b3 : sb3;

    // ---- MVLinear #1 (full, uniform): per-grade scale + e0*x + bias ----
    float xp[16];
    #pragma unroll
    for (int k = 0; k < 16; ++k) xp[k] = X[k] * W1[ct::GRADE[k]];
    xp[0]  += B1;
    xp[1]  += V1[1] * X[0];
    xp[5]  += V1[2] * X[2];
    xp[6]  += V1[2] * X[3];
    xp[7]  += V1[2] * X[4];
    xp[11] += V1[3] * X[8];
    xp[12] += V1[3] * X[9];
    xp[13] += V1[3] * X[10];

    // ---- gated GELU (exact), in place ----
    const float s0 = xp[0];
    const float gate = 0.5f * s0 * (1.0f + erff(s0 * 0.70710678118654752f));
    #pragma unroll
    for (int k = 0; k < 16; ++k) xp[k] *= gate;

    const float ps = X[15];

    // ---- half-split gather: p==0 -> k=0..7, p==1 -> k=8..15 ----
    float o[8];
    if (!podd) {
        float c1 = 0.f, c5 = 0.f, c6 = 0.f, c7 = 0.f;
        #pragma unroll
        for (int r = 0; r < 8; ++r) {
            const int k = r;
            float g = 0.f, h = 0.f;
            #pragma unroll
            for (int i = 0; i < 16; ++i) {
                #pragma unroll
                for (int j = 0; j < 16; ++j) {
                    if (ct::GP.sgn[i][j] > 0 && ct::GP.idx[i][j] == k)      g += X[i] * xp[j];
                    else if (ct::GP.sgn[i][j] < 0 && ct::GP.idx[i][j] == k) g -= X[i] * xp[j];
                    if (ct::JN.sgn[i][j] > 0 && ct::JN.idx[i][j] == k)      h += X[i] * xp[j];
                    else if (ct::JN.sgn[i][j] < 0 && ct::JN.idx[i][j] == k) h -= X[i] * xp[j];
                }
            }
            h *= ps;
            float val = g * W2G[ct::GRADE[k]] + h * W2J[ct::GRADE[k]];
            if (k == 0) { val += B2G + B2J; c1 = V2G[1] * g + V2J[1] * h; }
            if (k == 2) { c5 = V2G[2] * g + V2J[2] * h; }
            if (k == 3) { c6 = V2G[2] * g + V2J[2] * h; }
            if (k == 4) { c7 = V2G[2] * g + V2J[2] * h; }
            if (k == 1) val += c1;
            if (k == 5) val += c5;
            if (k == 6) val += c6;
            if (k == 7) val += c7;
            o[r] = val;
        }
    } else {
        float c11 = 0.f, c12 = 0.f, c13 = 0.f;
        #pragma unroll
        for (int r = 0; r < 8; ++r) {
            const int k = 8 + r;
            float g = 0.f, h = 0.f;
            #pragma unroll
            for (int i = 0; i < 16; ++i) {
                #pragma unroll
                for (int j = 0; j < 16; ++j) {
                    if (ct::GP.sgn[i][j] > 0 && ct::GP.idx[i][j] == k)      g += X[i] * xp[j];
                    else if (ct::GP.sgn[i][j] < 0 && ct::GP.idx[i][j] == k) g -= X[i] * xp[j];
                    if (ct::JN.sgn[i][j] > 0 && ct::JN.idx[i][j] == k)      h += X[i] * xp[j];
                    else if (ct::JN.sgn[i][j] < 0 && ct::JN.idx[i][j] == k) h -= X[i] * xp[j];
                }
            }
            h *= ps;
            float val = g * W2G[ct::GRADE[k]] + h * W2J[ct::GRADE[k]];
            if (k == 8)  { c11 = V2G[3] * g + V2J[3] * h; }
            if (k == 9)  { c12 = V2G[3] * g + V2J[3] * h; }
            if (k == 10) { c13 = V2G[3] * g + V2J[3] * h; }
            if (k == 11) val += c11;
            if (k == 12) val += c12;
            if (k == 13) val += c13;
            o[r] = val;
        }
    }

    // ---- store own half: mirrors the load addresses exactly ----
    float4* out4 = reinterpret_cast<float4*>(out);
    out4[2 * (size_t)t]     = make_float4(o[0], o[1], o[2], o[3]);
    out4[2 * (size_t)t + 1] = make_float4(o[4], o[5], o[6], o[7]);
}

extern "C" void kernel_launch(void* const* d_in, const int* in_sizes, int n_in,
                              void* d_out, int out_size, void* d_ws, size_t ws_size,
                              hipStream_t stream) {
    const float* x   = (const float*)d_in[0];
    const float* w1  = (const float*)d_in[1];
    const float* v1  = (const float*)d_in[2];
    const float* b1  = (const float*)d_in[3];
    const float* w2g = (const float*)d_in[4];
    const float* v2g = (const float*)d_in[5];
    const float* b2g = (const float*)d_in[6];
    const float* w2j = (const float*)d_in[7];
    const float* v2j = (const float*)d_in[8];
    const float* b2j = (const float*)d_in[9];
    float* out = (float*)d_out;

    const int n  = in_sizes[0] / 16;         // number of multivectors
    const int n2 = 2 * n;                    // half-MV threads
    const int block = 256;
    const int grid = (n2 + block - 1) / block;
    mvffn_kernel<<<grid, block, 0, stream>>>(x, w1, v1, b1, w2g, v2g, b2g,
                                             w2j, v2j, b2j, out, n2);
}

// Round 10
// 15.171 us; speedup vs baseline: 1.1718x; 1.1718x over previous
//
#include <hip/hip_runtime.h>
#include <math.h>

// ---------------------------------------------------------------------------
// Compile-time PGA Cl(3,0,1) tables. Basis ordering matches reference:
//   1, e0, e1, e2, e3, e01, e02, e03, e12, e13, e23, e012, e013, e023, e123, e0123
// Bitmask: bit0=e0, bit1=e1, bit2=e2, bit3=e3.
// ---------------------------------------------------------------------------
namespace ct {

constexpr int MASK[16] = {0, 1, 2, 4, 8, 3, 5, 9, 6, 10, 12, 7, 11, 13, 14, 15};
constexpr int IDX[16]  = {0, 1, 2, 5, 3, 6, 8, 11, 4, 7, 9, 12, 10, 13, 14, 15};
constexpr int GRADE[16] = {0, 1, 1, 1, 1, 2, 2, 2, 2, 2, 2, 3, 3, 3, 3, 4};

constexpr int popc(int v) { int c = 0; while (v) { c += v & 1; v >>= 1; } return c; }

constexpr int rs(int a, int b) {
    int s = 0;
    a >>= 1;
    while (a) { s += popc(a & b); a >>= 1; }
    return (s & 1) ? -1 : 1;
}

struct Tab { int sgn[16][16]; int idx[16][16]; };

constexpr Tab make_gp() {
    Tab t{};
    for (int i = 0; i < 16; ++i)
        for (int j = 0; j < 16; ++j) {
            int a = MASK[i], b = MASK[j];
            if (a & b & 1) { t.sgn[i][j] = 0; t.idx[i][j] = 0; }
            else           { t.sgn[i][j] = rs(a, b); t.idx[i][j] = IDX[a ^ b]; }
        }
    return t;
}

constexpr Tab make_jn() {
    Tab t{};
    for (int i = 0; i < 16; ++i)
        for (int j = 0; j < 16; ++j) {
            int a = MASK[i], b = MASK[j];
            int ca = 15 ^ a, cb = 15 ^ b;
            if (ca & cb) { t.sgn[i][j] = 0; t.idx[i][j] = 0; }
            else {
                int m = ca | cb;      // wedge in dual space
                int p = 15 ^ m;       // undual
                t.sgn[i][j] = rs(a, ca) * rs(b, cb) * rs(ca, cb) * rs(p, m);
                t.idx[i][j] = IDX[p];
            }
        }
    return t;
}

constexpr Tab GP = make_gp();
constexpr Tab JN = make_jn();

} // namespace ct

struct Params {
    float W1[5], W2G[5], W2J[5], V1[4], V2G[4], V2J[4];
    float B1, B2G, B2J;
};

// Full per-MV pipeline: MVLinear#1 -> gated gelu -> GP/JN gather with fused
// second linears. Gather form keeps the live set small (~50 floats).
__device__ __forceinline__ void mv_ffn_one(const float X[16], const Params& P, float o[16]) {
    float xp[16];
    #pragma unroll
    for (int k = 0; k < 16; ++k) xp[k] = X[k] * P.W1[ct::GRADE[k]];
    xp[0]  += P.B1;
    xp[1]  += P.V1[1] * X[0];
    xp[5]  += P.V1[2] * X[2];
    xp[6]  += P.V1[2] * X[3];
    xp[7]  += P.V1[2] * X[4];
    xp[11] += P.V1[3] * X[8];
    xp[12] += P.V1[3] * X[9];
    xp[13] += P.V1[3] * X[10];

    const float s0 = xp[0];
    const float gate = 0.5f * s0 * (1.0f + erff(s0 * 0.70710678118654752f));
    #pragma unroll
    for (int k = 0; k < 16; ++k) xp[k] *= gate;

    const float ps = X[15];

    float c1 = 0.f, c5 = 0.f, c6 = 0.f, c7 = 0.f, c11 = 0.f, c12 = 0.f, c13 = 0.f;
    #pragma unroll
    for (int k = 0; k < 16; ++k) {
        float g = 0.f, h = 0.f;
        #pragma unroll
        for (int i = 0; i < 16; ++i) {
            #pragma unroll
            for (int j = 0; j < 16; ++j) {
                if (ct::GP.sgn[i][j] > 0 && ct::GP.idx[i][j] == k)      g += X[i] * xp[j];
                else if (ct::GP.sgn[i][j] < 0 && ct::GP.idx[i][j] == k) g -= X[i] * xp[j];
                if (ct::JN.sgn[i][j] > 0 && ct::JN.idx[i][j] == k)      h += X[i] * xp[j];
                else if (ct::JN.sgn[i][j] < 0 && ct::JN.idx[i][j] == k) h -= X[i] * xp[j];
            }
        }
        h *= ps;

        float val = g * P.W2G[ct::GRADE[k]] + h * P.W2J[ct::GRADE[k]];
        if (k == 0)  { val += P.B2G + P.B2J; c1 = P.V2G[1] * g + P.V2J[1] * h; }
        if (k == 2)  { c5  = P.V2G[2] * g + P.V2J[2] * h; }
        if (k == 3)  { c6  = P.V2G[2] * g + P.V2J[2] * h; }
        if (k == 4)  { c7  = P.V2G[2] * g + P.V2J[2] * h; }
        if (k == 8)  { c11 = P.V2G[3] * g + P.V2J[3] * h; }
        if (k == 9)  { c12 = P.V2G[3] * g + P.V2J[3] * h; }
        if (k == 10) { c13 = P.V2G[3] * g + P.V2J[3] * h; }
        if (k == 1)  val += c1;
        if (k == 5)  val += c5;
        if (k == 6)  val += c6;
        if (k == 7)  val += c7;
        if (k == 11) val += c11;
        if (k == 12) val += c12;
        if (k == 13) val += c13;
        o[k] = val;
    }
}

// ---------------------------------------------------------------------------
// Software-pipelined: each thread processes TWO adjacent MVs (2t, 2t+1).
// All 8 loads issue up front (2x outstanding misses per wave); MV0's compute
// hides MV1's load latency; MV0's stores overlap MV1's compute. Compute body
// is identical for both MVs -> zero divergence (unlike the R9 split).
// 512 blocks -> 2 waves/SIMD, each with 2 pipelined iterations.
// ---------------------------------------------------------------------------
__global__ __launch_bounds__(256) void mvffn_kernel(
    const float* __restrict__ x,
    const float* __restrict__ w1,  const float* __restrict__ v1,  const float* __restrict__ b1,
    const float* __restrict__ w2g, const float* __restrict__ v2g, const float* __restrict__ b2g,
    const float* __restrict__ w2j, const float* __restrict__ v2j, const float* __restrict__ b2j,
    float* __restrict__ out, int n)
{
    const int t = blockIdx.x * blockDim.x + threadIdx.x;
    const int m0 = 2 * t;
    const int m1 = 2 * t + 1;
    if (m0 >= n) return;
    const bool has1 = (m1 < n);

    // ---- issue ALL loads up front: 8 x dwordx4 in flight per thread ----
    const float4* x4 = reinterpret_cast<const float4*>(x);
    float4 A0 = x4[4 * (size_t)m0 + 0];
    float4 A1 = x4[4 * (size_t)m0 + 1];
    float4 A2 = x4[4 * (size_t)m0 + 2];
    float4 A3 = x4[4 * (size_t)m0 + 3];
    float4 B0, B1v, B2, B3;
    if (has1) {
        B0  = x4[4 * (size_t)m1 + 0];
        B1v = x4[4 * (size_t)m1 + 1];
        B2  = x4[4 * (size_t)m1 + 2];
        B3  = x4[4 * (size_t)m1 + 3];
    }

    // ---- uniform parameters ----
    Params P;
    #pragma unroll
    for (int i = 0; i < 5; ++i) { P.W1[i] = w1[i]; P.W2G[i] = w2g[i]; P.W2J[i] = w2j[i]; }
    #pragma unroll
    for (int i = 0; i < 4; ++i) { P.V1[i] = v1[i]; P.V2G[i] = v2g[i]; P.V2J[i] = v2j[i]; }
    P.B1 = b1[0]; P.B2G = b2g[0]; P.B2J = b2j[0];

    float4* out4 = reinterpret_cast<float4*>(out);

    // ---- MV0: compute (waits only on A loads; B still in flight) + store ----
    {
        float X[16] = { A0.x, A0.y, A0.z, A0.w,  A1.x, A1.y, A1.z, A1.w,
                        A2.x, A2.y, A2.z, A2.w,  A3.x, A3.y, A3.z, A3.w };
        float o[16];
        mv_ffn_one(X, P, o);
        out4[4 * (size_t)m0 + 0] = make_float4(o[0],  o[1],  o[2],  o[3]);
        out4[4 * (size_t)m0 + 1] = make_float4(o[4],  o[5],  o[6],  o[7]);
        out4[4 * (size_t)m0 + 2] = make_float4(o[8],  o[9],  o[10], o[11]);
        out4[4 * (size_t)m0 + 3] = make_float4(o[12], o[13], o[14], o[15]);
    }

    // ---- MV1: compute (loads long since arrived) + store ----
    if (has1) {
        float X[16] = { B0.x,  B0.y,  B0.z,  B0.w,   B1v.x, B1v.y, B1v.z, B1v.w,
                        B2.x,  B2.y,  B2.z,  B2.w,   B3.x,  B3.y,  B3.z,  B3.w };
        float o[16];
        mv_ffn_one(X, P, o);
        out4[4 * (size_t)m1 + 0] = make_float4(o[0],  o[1],  o[2],  o[3]);
        out4[4 * (size_t)m1 + 1] = make_float4(o[4],  o[5],  o[6],  o[7]);
        out4[4 * (size_t)m1 + 2] = make_float4(o[8],  o[9],  o[10], o[11]);
        out4[4 * (size_t)m1 + 3] = make_float4(o[12], o[13], o[14], o[15]);
    }
}

extern "C" void kernel_launch(void* const* d_in, const int* in_sizes, int n_in,
                              void* d_out, int out_size, void* d_ws, size_t ws_size,
                              hipStream_t stream) {
    const float* x   = (const float*)d_in[0];
    const float* w1  = (const float*)d_in[1];
    const float* v1  = (const float*)d_in[2];
    const float* b1  = (const float*)d_in[3];
    const float* w2g = (const float*)d_in[4];
    const float* v2g = (const float*)d_in[5];
    const float* b2g = (const float*)d_in[6];
    const float* w2j = (const float*)d_in[7];
    const float* v2j = (const float*)d_in[8];
    const float* b2j = (const float*)d_in[9];
    float* out = (float*)d_out;

    const int n  = in_sizes[0] / 16;          // number of multivectors
    const int nt = (n + 1) / 2;               // threads (2 MVs each)
    const int block = 256;
    const int grid = (nt + block - 1) / block;
    mvffn_kernel<<<grid, block, 0, stream>>>(x, w1, v1, b1, w2g, v2g, b2g,
                                             w2j, v2j, b2j, out, n);
}

// Round 11
// 13.860 us; speedup vs baseline: 1.2827x; 1.0946x over previous
//
#include <hip/hip_runtime.h>
#include <math.h>

// ---------------------------------------------------------------------------
// Compile-time PGA Cl(3,0,1) tables.
// Blade basis ordering (matches reference):
//   1, e0, e1, e2, e3, e01, e02, e03, e12, e13, e23, e012, e013, e023, e123, e0123
// Bitmask representation: bit0=e0, bit1=e1, bit2=e2, bit3=e3.
// ---------------------------------------------------------------------------
namespace ct {

constexpr int MASK[16] = {0, 1, 2, 4, 8, 3, 5, 9, 6, 10, 12, 7, 11, 13, 14, 15};
constexpr int IDX[16]  = {0, 1, 2, 5, 3, 6, 8, 11, 4, 7, 9, 12, 10, 13, 14, 15};
constexpr int GRADE[16] = {0, 1, 1, 1, 1, 2, 2, 2, 2, 2, 2, 3, 3, 3, 3, 4};

constexpr int popc(int v) { int c = 0; while (v) { c += v & 1; v >>= 1; } return c; }

constexpr int rs(int a, int b) {
    int s = 0;
    a >>= 1;
    while (a) { s += popc(a & b); a >>= 1; }
    return (s & 1) ? -1 : 1;
}

struct Tab { int sgn[16][16]; int idx[16][16]; };

constexpr Tab make_gp() {
    Tab t{};
    for (int i = 0; i < 16; ++i)
        for (int j = 0; j < 16; ++j) {
            int a = MASK[i], b = MASK[j];
            if (a & b & 1) { t.sgn[i][j] = 0; t.idx[i][j] = 0; }
            else           { t.sgn[i][j] = rs(a, b); t.idx[i][j] = IDX[a ^ b]; }
        }
    return t;
}

constexpr Tab make_jn() {
    Tab t{};
    for (int i = 0; i < 16; ++i)
        for (int j = 0; j < 16; ++j) {
            int a = MASK[i], b = MASK[j];
            int ca = 15 ^ a, cb = 15 ^ b;
            if (ca & cb) { t.sgn[i][j] = 0; t.idx[i][j] = 0; }
            else {
                int m = ca | cb;      // wedge in dual space
                int p = 15 ^ m;       // undual
                t.sgn[i][j] = rs(a, ca) * rs(b, cb) * rs(ca, cb) * rs(p, m);
                t.idx[i][j] = IDX[p];
            }
        }
    return t;
}

constexpr Tab GP = make_gp();
constexpr Tab JN = make_jn();

} // namespace ct

// ---------------------------------------------------------------------------
// One thread per multivector. Coalesced global I/O via WAVE-PRIVATE LDS slabs
// (no __syncthreads). Bilinear forms in GATHER form: per output component k,
// sum its GP/JN terms into two scalars and fold the second linears in
// immediately -> peak live set ~X[16]+xp[16]+o[] instead of +gp[16]+jn[16].
// Best-measured configuration of this session (13.0 us).
// ---------------------------------------------------------------------------
__global__ __launch_bounds__(256) void mvffn_kernel(
    const float* __restrict__ x,
    const float* __restrict__ w1,  const float* __restrict__ v1,  const float* __restrict__ b1,
    const float* __restrict__ w2g, const float* __restrict__ v2g, const float* __restrict__ b2g,
    const float* __restrict__ w2j, const float* __restrict__ v2j, const float* __restrict__ b2j,
    float* __restrict__ out, int n)
{
    const int tid  = threadIdx.x;
    const int lane = tid & 63;
    const int wv   = tid >> 6;                    // wave id within block (0..3)
    const int mv0  = blockIdx.x * 256;            // first MV of this block
    const int mv   = mv0 + tid;
    const bool full = (mv0 + 256 <= n);

    __shared__ float4 sh[4][64 * 5];              // 4 wave-private 5 KB slabs

    // ---- load: coalesced global -> LDS -> per-thread registers ----
    float X[16];
    if (full) {
        const float4* gx = reinterpret_cast<const float4*>(x)
                         + (size_t)(mv0 + wv * 64) * 4;     // wave's 4 KB slab
        #pragma unroll
        for (int k = 0; k < 4; ++k) {
            const int u = lane + 64 * k;                    // coalesced, 16 lines/inst
            sh[wv][(u >> 2) * 5 + (u & 3)] = gx[u];
        }
        __builtin_amdgcn_wave_barrier();                    // keep write->read order
        #pragma unroll
        for (int j = 0; j < 4; ++j) {
            float4 q = sh[wv][lane * 5 + j];
            X[4 * j + 0] = q.x; X[4 * j + 1] = q.y; X[4 * j + 2] = q.z; X[4 * j + 3] = q.w;
        }
        __builtin_amdgcn_wave_barrier();                    // reads before slab reuse
    } else if (mv < n) {                                    // tail block (rare)
        const float4* xv = reinterpret_cast<const float4*>(x) + (size_t)mv * 4;
        #pragma unroll
        for (int j = 0; j < 4; ++j) {
            float4 q = xv[j];
            X[4 * j + 0] = q.x; X[4 * j + 1] = q.y; X[4 * j + 2] = q.z; X[4 * j + 3] = q.w;
        }
    }

    float o[16];
    if (full || mv < n) {
        // ---- uniform parameters ----
        float W1[5], W2G[5], W2J[5], V1[4], V2G[4], V2J[4];
        #pragma unroll
        for (int i = 0; i < 5; ++i) { W1[i] = w1[i]; W2G[i] = w2g[i]; W2J[i] = w2j[i]; }
        #pragma unroll
        for (int i = 0; i < 4; ++i) { V1[i] = v1[i]; V2G[i] = v2g[i]; V2J[i] = v2j[i]; }
        const float B1 = b1[0], B2G = b2g[0], B2J = b2j[0];

        // ---- MVLinear #1: per-grade scale + e0*x branch + scalar bias ----
        float xp[16];
        #pragma unroll
        for (int k = 0; k < 16; ++k) xp[k] = X[k] * W1[ct::GRADE[k]];
        xp[0]  += B1;
        xp[1]  += V1[1] * X[0];                     // e0   <- 1
        xp[5]  += V1[2] * X[2];                     // e01  <- e1
        xp[6]  += V1[2] * X[3];                     // e02  <- e2
        xp[7]  += V1[2] * X[4];                     // e03  <- e3
        xp[11] += V1[3] * X[8];                     // e012 <- e12
        xp[12] += V1[3] * X[9];                     // e013 <- e13
        xp[13] += V1[3] * X[10];                    // e023 <- e23

        // ---- gated GELU (exact), in place: xp becomes x_gated ----
        const float s0 = xp[0];
        const float gate = 0.5f * s0 * (1.0f + erff(s0 * 0.70710678118654752f));
        #pragma unroll
        for (int k = 0; k < 16; ++k) xp[k] *= gate;

        const float ps = X[15];

        // ---- bilinear forms in GATHER form + fused second linears ----
        // Short-lived stashes for the e0-branch cross terms (source k < dest k).
        float c1 = 0.f, c5 = 0.f, c6 = 0.f, c7 = 0.f, c11 = 0.f, c12 = 0.f, c13 = 0.f;

        #pragma unroll
        for (int k = 0; k < 16; ++k) {
            float g = 0.f, h = 0.f;
            #pragma unroll
            for (int i = 0; i < 16; ++i) {
                #pragma unroll
                for (int j = 0; j < 16; ++j) {
                    if (ct::GP.sgn[i][j] > 0 && ct::GP.idx[i][j] == k)      g += X[i] * xp[j];
                    else if (ct::GP.sgn[i][j] < 0 && ct::GP.idx[i][j] == k) g -= X[i] * xp[j];
                    if (ct::JN.sgn[i][j] > 0 && ct::JN.idx[i][j] == k)      h += X[i] * xp[j];
                    else if (ct::JN.sgn[i][j] < 0 && ct::JN.idx[i][j] == k) h -= X[i] * xp[j];
                }
            }
            h *= ps;                                 // join gated by reference ps

            float val = g * W2G[ct::GRADE[k]] + h * W2J[ct::GRADE[k]];
            // e0-branch cross contributions (dest index > k, stash now)
            if (k == 0)  { val += B2G + B2J; c1  = V2G[1] * g + V2J[1] * h; }
            if (k == 2)  { c5  = V2G[2] * g + V2J[2] * h; }
            if (k == 3)  { c6  = V2G[2] * g + V2J[2] * h; }
            if (k == 4)  { c7  = V2G[2] * g + V2J[2] * h; }
            if (k == 8)  { c11 = V2G[3] * g + V2J[3] * h; }
            if (k == 9)  { c12 = V2G[3] * g + V2J[3] * h; }
            if (k == 10) { c13 = V2G[3] * g + V2J[3] * h; }
            // fold stashed cross terms into their destination
            if (k == 1)  val += c1;
            if (k == 5)  val += c5;
            if (k == 6)  val += c6;
            if (k == 7)  val += c7;
            if (k == 11) val += c11;
            if (k == 12) val += c12;
            if (k == 13) val += c13;
            o[k] = val;
        }
    }

    // ---- store: registers -> LDS -> coalesced global ----
    if (full) {
        #pragma unroll
        for (int j = 0; j < 4; ++j)
            sh[wv][lane * 5 + j] =
                make_float4(o[4 * j + 0], o[4 * j + 1], o[4 * j + 2], o[4 * j + 3]);
        __builtin_amdgcn_wave_barrier();
        float4* gy = reinterpret_cast<float4*>(out) + (size_t)(mv0 + wv * 64) * 4;
        #pragma unroll
        for (int k = 0; k < 4; ++k) {
            const int u = lane + 64 * k;                    // coalesced store
            gy[u] = sh[wv][(u >> 2) * 5 + (u & 3)];
        }
    } else if (mv < n) {
        float4* ov = reinterpret_cast<float4*>(out) + (size_t)mv * 4;
        #pragma unroll
        for (int j = 0; j < 4; ++j)
            ov[j] = make_float4(o[4 * j + 0], o[4 * j + 1], o[4 * j + 2], o[4 * j + 3]);
    }
}

extern "C" void kernel_launch(void* const* d_in, const int* in_sizes, int n_in,
                              void* d_out, int out_size, void* d_ws, size_t ws_size,
                              hipStream_t stream) {
    const float* x   = (const float*)d_in[0];
    const float* w1  = (const float*)d_in[1];
    const float* v1  = (const float*)d_in[2];
    const float* b1  = (const float*)d_in[3];
    const float* w2g = (const float*)d_in[4];
    const float* v2g = (const float*)d_in[5];
    const float* b2g = (const float*)d_in[6];
    const float* w2j = (const float*)d_in[7];
    const float* v2j = (const float*)d_in[8];
    const float* b2j = (const float*)d_in[9];
    float* out = (float*)d_out;

    const int n = in_sizes[0] / 16;          // number of multivectors
    const int block = 256;
    const int grid = (n + block - 1) / block;
    mvffn_kernel<<<grid, block, 0, stream>>>(x, w1, v1, b1, w2g, v2g, b2g,
                                             w2j, v2j, b2j, out, n);
}